// Round 5
// baseline (179.666 us; speedup 1.0000x reference)
//
#include <hip/hip_runtime.h>

// BCE-sum reduction over 2×128MiB fp32 inputs → scalar.
// R4: stage-1 delivers ~6.1 TB/s (97% of the 6.29 TB/s measured stream
// ceiling); remaining slack is the 2nd kernel + launch gap (~4 µs).
// R5: single-kernel hierarchical last-block finisher — 64 group counters
// (32 arrivals each) + 1 super counter (64 arrivals); max same-line atomic
// depth is 64, so no 2048-deep burst. Finisher reads partials with
// agent-scope atomic loads (coherent past per-XCD L2) and writes d_out.

#define NB     2048   // stage-1 grid
#define BLK    256
#define GROUPS 64     // 32 blocks per group
#define GRP_SHIFT 5   // bid >> 5 -> group

// max(ln x, -100) = ln2 * max(log2 x, -100/ln2); accumulate positive sum in
// log2 domain, scale by -ln2 once per block.
#define LOG2_CLAMP -144.26950408889634f
#define NEG_LN2    -0.6931471805599453f

__device__ __forceinline__ float bce4_log2(float4 p, float4 t) {
    float s, lp, l1;
    lp = fmaxf(__log2f(p.x),        LOG2_CLAMP);
    l1 = fmaxf(__log2f(1.0f - p.x), LOG2_CLAMP);
    s  = l1 + t.x * (lp - l1);
    lp = fmaxf(__log2f(p.y),        LOG2_CLAMP);
    l1 = fmaxf(__log2f(1.0f - p.y), LOG2_CLAMP);
    s += l1 + t.y * (lp - l1);
    lp = fmaxf(__log2f(p.z),        LOG2_CLAMP);
    l1 = fmaxf(__log2f(1.0f - p.z), LOG2_CLAMP);
    s += l1 + t.z * (lp - l1);
    lp = fmaxf(__log2f(p.w),        LOG2_CLAMP);
    l1 = fmaxf(__log2f(1.0f - p.w), LOG2_CLAMP);
    s += l1 + t.w * (lp - l1);
    return s;
}

__device__ __forceinline__ float block_reduce(float acc) {
    #pragma unroll
    for (int off = 32; off > 0; off >>= 1)
        acc += __shfl_down(acc, off, 64);
    __shared__ float wave_sums[4];
    int lane = threadIdx.x & 63;
    int wave = threadIdx.x >> 6;
    if (lane == 0) wave_sums[wave] = acc;
    __syncthreads();
    float s = 0.0f;
    if (wave == 0) {
        s = (lane < 4) ? wave_sums[lane] : 0.0f;
        #pragma unroll
        for (int off = 2; off > 0; off >>= 1)
            s += __shfl_down(s, off, 64);
    }
    return s;  // valid in (wave 0, lane 0)
}

__global__ void __launch_bounds__(BLK) bce_fused_kernel(
        const float4* __restrict__ p4,
        const float4* __restrict__ t4,
        float* __restrict__ partials,   // [NB] in d_ws
        int* __restrict__ counters,     // [GROUPS+1] in d_ws, zeroed per call
        float* __restrict__ out,
        int n4) {
    const int chunk = n4 / gridDim.x;               // 4096 for n4 = 8M
    const int base  = blockIdx.x * chunk;

    float a0 = 0.f, a1 = 0.f, a2 = 0.f, a3 = 0.f,
          a4 = 0.f, a5 = 0.f, a6 = 0.f, a7 = 0.f;

    int o = 0;
    for (; o + 8 * BLK <= chunk; o += 8 * BLK) {
        int i = base + o + threadIdx.x;
        float4 p0 = p4[i];            float4 p1 = p4[i + 1 * BLK];
        float4 p2 = p4[i + 2 * BLK];  float4 p3 = p4[i + 3 * BLK];
        float4 p4v = p4[i + 4 * BLK]; float4 p5 = p4[i + 5 * BLK];
        float4 p6 = p4[i + 6 * BLK];  float4 p7 = p4[i + 7 * BLK];
        float4 t0 = t4[i];            float4 t1 = t4[i + 1 * BLK];
        float4 t2 = t4[i + 2 * BLK];  float4 t3 = t4[i + 3 * BLK];
        float4 t4v = t4[i + 4 * BLK]; float4 t5 = t4[i + 5 * BLK];
        float4 t6 = t4[i + 6 * BLK];  float4 t7 = t4[i + 7 * BLK];
        a0 += bce4_log2(p0, t0);   a1 += bce4_log2(p1, t1);
        a2 += bce4_log2(p2, t2);   a3 += bce4_log2(p3, t3);
        a4 += bce4_log2(p4v, t4v); a5 += bce4_log2(p5, t5);
        a6 += bce4_log2(p6, t6);   a7 += bce4_log2(p7, t7);
    }
    for (; o < chunk; o += BLK) {               // generality guard
        int i = base + o + threadIdx.x;
        if (o + (int)threadIdx.x < chunk)
            a0 += bce4_log2(p4[i], t4[i]);
    }
    if (blockIdx.x == 0) {                      // generality guard
        for (int i = (int)gridDim.x * chunk + threadIdx.x; i < n4; i += BLK)
            a0 += bce4_log2(p4[i], t4[i]);
    }

    float s = block_reduce(((a0 + a1) + (a2 + a3)) + ((a4 + a5) + (a6 + a7)));

    // --- hierarchical last-block rendezvous ---
    __shared__ bool s_last;
    if (threadIdx.x == 0) {
        partials[blockIdx.x] = NEG_LN2 * s;
        __threadfence();  // release partials to device scope
        bool last = false;
        int g = blockIdx.x >> GRP_SHIFT;
        int prev = __hip_atomic_fetch_add(&counters[g], 1,
                       __ATOMIC_ACQ_REL, __HIP_MEMORY_SCOPE_AGENT);
        if (prev == (NB / GROUPS) - 1) {        // last in group (32 arrivals)
            int prev2 = __hip_atomic_fetch_add(&counters[GROUPS], 1,
                            __ATOMIC_ACQ_REL, __HIP_MEMORY_SCOPE_AGENT);
            last = (prev2 == GROUPS - 1);       // last overall (64 arrivals)
        }
        s_last = last;
    }
    __syncthreads();

    if (s_last) {
        // All 2048 partials are released; agent-scope loads read past any
        // stale per-XCD L2 copy. Fixed summation order -> deterministic.
        float acc = 0.0f;
        for (int i = threadIdx.x; i < NB; i += BLK)
            acc += __hip_atomic_load(&partials[i],
                       __ATOMIC_RELAXED, __HIP_MEMORY_SCOPE_AGENT);
        float r = block_reduce(acc);
        if (threadIdx.x == 0)
            out[0] = r;   // overwrites poison
    }
}

// Fallback (tiny ws): atomic path, two kernels not needed.
__global__ void __launch_bounds__(BLK) bce_atomic_kernel(
        const float4* __restrict__ p4,
        const float4* __restrict__ t4,
        float* __restrict__ out,
        int n4) {
    const int tid    = blockIdx.x * blockDim.x + threadIdx.x;
    const int stride = gridDim.x * blockDim.x;
    float a = 0.0f;
    for (int i = tid; i < n4; i += stride)
        a += bce4_log2(p4[i], t4[i]);
    float s = block_reduce(a);
    if (threadIdx.x == 0)
        atomicAdd(out, NEG_LN2 * s);
}

extern "C" void kernel_launch(void* const* d_in, const int* in_sizes, int n_in,
                              void* d_out, int out_size, void* d_ws, size_t ws_size,
                              hipStream_t stream) {
    const float* predict = (const float*)d_in[0];
    const float* target  = (const float*)d_in[1];
    float* out = (float*)d_out;

    int n  = in_sizes[0];      // 33,554,432 (divisible by 4)
    int n4 = n / 4;

    // ws layout: [0,512) counters (GROUPS+1 ints, zeroed per call),
    //            [512, 512 + NB*4) partials.
    const size_t need = 512 + (size_t)NB * sizeof(float);
    if (ws_size >= need && n4 >= NB) {
        int*   counters = (int*)d_ws;
        float* partials = (float*)((char*)d_ws + 512);
        hipMemsetAsync(d_ws, 0, 512, stream);
        bce_fused_kernel<<<NB, BLK, 0, stream>>>(
            (const float4*)predict, (const float4*)target,
            partials, counters, out, n4);
    } else {
        hipMemsetAsync(d_out, 0, sizeof(float), stream);
        bce_atomic_kernel<<<NB, BLK, 0, stream>>>(
            (const float4*)predict, (const float4*)target, out, n4);
    }
}

// Round 6
// 53.451 us; speedup vs baseline: 3.3613x; 3.3613x over previous
//
#include <hip/hip_runtime.h>

// BCE-sum reduction over 2×128MiB fp32 inputs → scalar.
// R5 post-mortem: fused finisher regressed 47.5→180 µs because
// __threadfence + acq_rel agent atomics emit per-block L2
// writeback-invalidate (×2048 ≈ 250 µs tail) on non-coherent per-XCD L2s.
// R6: same fusion, but ALL cross-block comms are RELAXED agent-scope atomics
// (write-through to coherence point, no cache maintenance emitted):
//   partial  -> __hip_atomic_store relaxed/agent (write-through)
//   ordering -> explicit s_waitcnt vmcnt(0) (store complete before counter RMW)
//   counters -> relaxed agent fetch_add, hierarchical (depth <= 64)
//   finisher -> relaxed agent loads (L2-bypass), fixed summation order.

#define NB     2048   // stage-1 grid
#define BLK    256
#define GROUPS 64     // 32 blocks per group
#define GRP_SHIFT 5   // bid >> 5 -> group

// max(ln x, -100) = ln2 * max(log2 x, -100/ln2); accumulate positive sum in
// log2 domain, scale by -ln2 once per block.
#define LOG2_CLAMP -144.26950408889634f
#define NEG_LN2    -0.6931471805599453f

__device__ __forceinline__ float bce4_log2(float4 p, float4 t) {
    float s, lp, l1;
    lp = fmaxf(__log2f(p.x),        LOG2_CLAMP);
    l1 = fmaxf(__log2f(1.0f - p.x), LOG2_CLAMP);
    s  = l1 + t.x * (lp - l1);
    lp = fmaxf(__log2f(p.y),        LOG2_CLAMP);
    l1 = fmaxf(__log2f(1.0f - p.y), LOG2_CLAMP);
    s += l1 + t.y * (lp - l1);
    lp = fmaxf(__log2f(p.z),        LOG2_CLAMP);
    l1 = fmaxf(__log2f(1.0f - p.z), LOG2_CLAMP);
    s += l1 + t.z * (lp - l1);
    lp = fmaxf(__log2f(p.w),        LOG2_CLAMP);
    l1 = fmaxf(__log2f(1.0f - p.w), LOG2_CLAMP);
    s += l1 + t.w * (lp - l1);
    return s;
}

__device__ __forceinline__ float block_reduce(float acc) {
    #pragma unroll
    for (int off = 32; off > 0; off >>= 1)
        acc += __shfl_down(acc, off, 64);
    __shared__ float wave_sums[4];
    int lane = threadIdx.x & 63;
    int wave = threadIdx.x >> 6;
    if (lane == 0) wave_sums[wave] = acc;
    __syncthreads();
    float s = 0.0f;
    if (wave == 0) {
        s = (lane < 4) ? wave_sums[lane] : 0.0f;
        #pragma unroll
        for (int off = 2; off > 0; off >>= 1)
            s += __shfl_down(s, off, 64);
    }
    return s;  // valid in (wave 0, lane 0)
}

__global__ void __launch_bounds__(BLK) bce_fused_kernel(
        const float4* __restrict__ p4,
        const float4* __restrict__ t4,
        float* __restrict__ partials,   // [NB] in d_ws
        int* __restrict__ counters,     // [GROUPS+1] in d_ws, zeroed per call
        float* __restrict__ out,
        int n4) {
    const int chunk = n4 / gridDim.x;               // 4096 for n4 = 8M
    const int base  = blockIdx.x * chunk;

    float a0 = 0.f, a1 = 0.f, a2 = 0.f, a3 = 0.f,
          a4 = 0.f, a5 = 0.f, a6 = 0.f, a7 = 0.f;

    int o = 0;
    for (; o + 8 * BLK <= chunk; o += 8 * BLK) {
        int i = base + o + threadIdx.x;
        float4 p0 = p4[i];            float4 p1 = p4[i + 1 * BLK];
        float4 p2 = p4[i + 2 * BLK];  float4 p3 = p4[i + 3 * BLK];
        float4 p4v = p4[i + 4 * BLK]; float4 p5 = p4[i + 5 * BLK];
        float4 p6 = p4[i + 6 * BLK];  float4 p7 = p4[i + 7 * BLK];
        float4 t0 = t4[i];            float4 t1 = t4[i + 1 * BLK];
        float4 t2 = t4[i + 2 * BLK];  float4 t3 = t4[i + 3 * BLK];
        float4 t4v = t4[i + 4 * BLK]; float4 t5 = t4[i + 5 * BLK];
        float4 t6 = t4[i + 6 * BLK];  float4 t7 = t4[i + 7 * BLK];
        a0 += bce4_log2(p0, t0);   a1 += bce4_log2(p1, t1);
        a2 += bce4_log2(p2, t2);   a3 += bce4_log2(p3, t3);
        a4 += bce4_log2(p4v, t4v); a5 += bce4_log2(p5, t5);
        a6 += bce4_log2(p6, t6);   a7 += bce4_log2(p7, t7);
    }
    for (; o < chunk; o += BLK) {               // generality guard
        int i = base + o + threadIdx.x;
        if (o + (int)threadIdx.x < chunk)
            a0 += bce4_log2(p4[i], t4[i]);
    }
    if (blockIdx.x == 0) {                      // generality guard
        for (int i = (int)gridDim.x * chunk + threadIdx.x; i < n4; i += BLK)
            a0 += bce4_log2(p4[i], t4[i]);
    }

    float s = block_reduce(((a0 + a1) + (a2 + a3)) + ((a4 + a5) + (a6 + a7)));

    // --- last-block rendezvous: relaxed write-through atomics only, no fences ---
    __shared__ bool s_last;
    if (threadIdx.x == 0) {
        // Write-through atomic store: value lands at the coherence point,
        // never sits dirty in this XCD's L2. No cache maintenance emitted.
        __hip_atomic_store(&partials[blockIdx.x], NEG_LN2 * s,
                           __ATOMIC_RELAXED, __HIP_MEMORY_SCOPE_AGENT);
        // Order: partial store must COMPLETE before the counter RMW issues.
        asm volatile("s_waitcnt vmcnt(0)" ::: "memory");
        bool last = false;
        int g = blockIdx.x >> GRP_SHIFT;
        int prev = __hip_atomic_fetch_add(&counters[g], 1,
                       __ATOMIC_RELAXED, __HIP_MEMORY_SCOPE_AGENT);
        if (prev == (NB / GROUPS) - 1) {        // last in group (32 arrivals)
            // prev is data-dependent on the completed group RMW.
            int prev2 = __hip_atomic_fetch_add(&counters[GROUPS], 1,
                            __ATOMIC_RELAXED, __HIP_MEMORY_SCOPE_AGENT);
            last = (prev2 == GROUPS - 1);       // last overall (64 arrivals)
        }
        s_last = last;
    }
    __syncthreads();

    if (s_last) {
        // All partials were write-through-complete before their counter
        // increments; our observation of the final count orders after them.
        // Relaxed agent loads bypass L1/L2 and read the coherence point.
        // Fixed summation order -> deterministic.
        float acc = 0.0f;
        for (int i = threadIdx.x; i < NB; i += BLK)
            acc += __hip_atomic_load(&partials[i],
                       __ATOMIC_RELAXED, __HIP_MEMORY_SCOPE_AGENT);
        float r = block_reduce(acc);
        if (threadIdx.x == 0)
            out[0] = r;   // overwrites poison
    }
}

// Fallback (tiny ws): atomic path.
__global__ void __launch_bounds__(BLK) bce_atomic_kernel(
        const float4* __restrict__ p4,
        const float4* __restrict__ t4,
        float* __restrict__ out,
        int n4) {
    const int tid    = blockIdx.x * blockDim.x + threadIdx.x;
    const int stride = gridDim.x * blockDim.x;
    float a = 0.0f;
    for (int i = tid; i < n4; i += stride)
        a += bce4_log2(p4[i], t4[i]);
    float s = block_reduce(a);
    if (threadIdx.x == 0)
        atomicAdd(out, NEG_LN2 * s);
}

extern "C" void kernel_launch(void* const* d_in, const int* in_sizes, int n_in,
                              void* d_out, int out_size, void* d_ws, size_t ws_size,
                              hipStream_t stream) {
    const float* predict = (const float*)d_in[0];
    const float* target  = (const float*)d_in[1];
    float* out = (float*)d_out;

    int n  = in_sizes[0];      // 33,554,432 (divisible by 4)
    int n4 = n / 4;

    // ws layout: [0,512) counters (GROUPS+1 ints, zeroed per call),
    //            [512, 512 + NB*4) partials.
    const size_t need = 512 + (size_t)NB * sizeof(float);
    if (ws_size >= need && n4 >= NB) {
        int*   counters = (int*)d_ws;
        float* partials = (float*)((char*)d_ws + 512);
        hipMemsetAsync(d_ws, 0, 512, stream);
        bce_fused_kernel<<<NB, BLK, 0, stream>>>(
            (const float4*)predict, (const float4*)target,
            partials, counters, out, n4);
    } else {
        hipMemsetAsync(d_out, 0, sizeof(float), stream);
        bce_atomic_kernel<<<NB, BLK, 0, stream>>>(
            (const float4*)predict, (const float4*)target, out, n4);
    }
}

// Round 7
// 47.277 us; speedup vs baseline: 3.8003x; 1.1306x over previous
//
#include <hip/hip_runtime.h>

// BCE-sum reduction over 2×128MiB fp32 inputs → scalar.
// Final form (R4 structure, restored after fusion A/B):
//  - R3: two-stage reduce removed the 2048-way same-address atomic drain
//    (65.7 -> 50.9 µs).
//  - R4: unroll×8 + block-contiguous chunks -> ~6.1 TB/s delivered
//    (47.5 µs; 90% of the ~6.3 TB/s delivery ceiling; FETCH=134 MB, the
//    other half L3-served).
//  - R5 (fence rendezvous): 180 µs — per-block L2 writeback-inv, REJECTED.
//  - R6 (relaxed-atomic rendezvous): 53.5 µs — still worse than the
//    2nd-kernel launch, REJECTED. Two-kernel is measured-best.

#define NB  2048   // stage-1 grid
#define BLK 256

// max(ln x, -100) = ln2 * max(log2 x, -100/ln2); accumulate positive sum in
// log2 domain, scale by -ln2 once per block.
#define LOG2_CLAMP -144.26950408889634f
#define NEG_LN2    -0.6931471805599453f

__device__ __forceinline__ float bce4_log2(float4 p, float4 t) {
    float s, lp, l1;
    lp = fmaxf(__log2f(p.x),        LOG2_CLAMP);
    l1 = fmaxf(__log2f(1.0f - p.x), LOG2_CLAMP);
    s  = l1 + t.x * (lp - l1);
    lp = fmaxf(__log2f(p.y),        LOG2_CLAMP);
    l1 = fmaxf(__log2f(1.0f - p.y), LOG2_CLAMP);
    s += l1 + t.y * (lp - l1);
    lp = fmaxf(__log2f(p.z),        LOG2_CLAMP);
    l1 = fmaxf(__log2f(1.0f - p.z), LOG2_CLAMP);
    s += l1 + t.z * (lp - l1);
    lp = fmaxf(__log2f(p.w),        LOG2_CLAMP);
    l1 = fmaxf(__log2f(1.0f - p.w), LOG2_CLAMP);
    s += l1 + t.w * (lp - l1);
    return s;
}

__device__ __forceinline__ float block_reduce(float acc) {
    #pragma unroll
    for (int off = 32; off > 0; off >>= 1)
        acc += __shfl_down(acc, off, 64);
    __shared__ float wave_sums[4];
    int lane = threadIdx.x & 63;
    int wave = threadIdx.x >> 6;
    if (lane == 0) wave_sums[wave] = acc;
    __syncthreads();
    float s = 0.0f;
    if (wave == 0) {
        s = (lane < 4) ? wave_sums[lane] : 0.0f;
        #pragma unroll
        for (int off = 2; off > 0; off >>= 1)
            s += __shfl_down(s, off, 64);
    }
    return s;  // valid in (wave 0, lane 0)
}

__global__ void __launch_bounds__(BLK) bce_partial_kernel(
        const float4* __restrict__ p4,
        const float4* __restrict__ t4,
        float* __restrict__ partials,
        int n4) {
    // Block-contiguous chunk: block b owns [b*chunk, (b+1)*chunk).
    const int chunk = n4 / gridDim.x;               // 4096 for n4 = 8M
    const int base  = blockIdx.x * chunk;

    float a0 = 0.f, a1 = 0.f, a2 = 0.f, a3 = 0.f,
          a4 = 0.f, a5 = 0.f, a6 = 0.f, a7 = 0.f;

    int o = 0;
    // Main loop: 8 p-loads + 8 t-loads issued back-to-back (16 in flight).
    for (; o + 8 * BLK <= chunk; o += 8 * BLK) {
        int i = base + o + threadIdx.x;
        float4 p0 = p4[i];            float4 p1 = p4[i + 1 * BLK];
        float4 p2 = p4[i + 2 * BLK];  float4 p3 = p4[i + 3 * BLK];
        float4 p4v = p4[i + 4 * BLK]; float4 p5 = p4[i + 5 * BLK];
        float4 p6 = p4[i + 6 * BLK];  float4 p7 = p4[i + 7 * BLK];
        float4 t0 = t4[i];            float4 t1 = t4[i + 1 * BLK];
        float4 t2 = t4[i + 2 * BLK];  float4 t3 = t4[i + 3 * BLK];
        float4 t4v = t4[i + 4 * BLK]; float4 t5 = t4[i + 5 * BLK];
        float4 t6 = t4[i + 6 * BLK];  float4 t7 = t4[i + 7 * BLK];
        a0 += bce4_log2(p0, t0);   a1 += bce4_log2(p1, t1);
        a2 += bce4_log2(p2, t2);   a3 += bce4_log2(p3, t3);
        a4 += bce4_log2(p4v, t4v); a5 += bce4_log2(p5, t5);
        a6 += bce4_log2(p6, t6);   a7 += bce4_log2(p7, t7);
    }
    // Chunk tail (unused for the fixed shape; generality guard).
    for (; o < chunk; o += BLK) {
        int i = base + o + threadIdx.x;
        if (o + (int)threadIdx.x < chunk)
            a0 += bce4_log2(p4[i], t4[i]);
    }
    // Global tail beyond NB*chunk (unused for fixed shape): block 0 sweeps.
    if (blockIdx.x == 0) {
        for (int i = (int)gridDim.x * chunk + threadIdx.x; i < n4; i += BLK)
            a0 += bce4_log2(p4[i], t4[i]);
    }

    float s = block_reduce(((a0 + a1) + (a2 + a3)) + ((a4 + a5) + (a6 + a7)));
    if (threadIdx.x == 0)
        partials[blockIdx.x] = NEG_LN2 * s;   // plain store, no atomic
}

__global__ void __launch_bounds__(BLK) bce_final_kernel(
        const float* __restrict__ partials,
        float* __restrict__ out,
        int nb) {
    float acc = 0.0f;
    for (int i = threadIdx.x; i < nb; i += BLK)
        acc += partials[i];
    float s = block_reduce(acc);
    if (threadIdx.x == 0)
        out[0] = s;   // overwrites poison; no memset needed
}

// Fallback (tiny ws): atomic path.
__global__ void __launch_bounds__(BLK) bce_atomic_kernel(
        const float4* __restrict__ p4,
        const float4* __restrict__ t4,
        float* __restrict__ out,
        int n4) {
    const int tid    = blockIdx.x * blockDim.x + threadIdx.x;
    const int stride = gridDim.x * blockDim.x;
    float a = 0.0f;
    for (int i = tid; i < n4; i += stride)
        a += bce4_log2(p4[i], t4[i]);
    float s = block_reduce(a);
    if (threadIdx.x == 0)
        atomicAdd(out, NEG_LN2 * s);
}

extern "C" void kernel_launch(void* const* d_in, const int* in_sizes, int n_in,
                              void* d_out, int out_size, void* d_ws, size_t ws_size,
                              hipStream_t stream) {
    const float* predict = (const float*)d_in[0];
    const float* target  = (const float*)d_in[1];
    float* out = (float*)d_out;

    int n  = in_sizes[0];      // 33,554,432 (divisible by 4)
    int n4 = n / 4;

    if (ws_size >= NB * sizeof(float) && n4 >= NB) {
        float* partials = (float*)d_ws;
        bce_partial_kernel<<<NB, BLK, 0, stream>>>(
            (const float4*)predict, (const float4*)target, partials, n4);
        bce_final_kernel<<<1, BLK, 0, stream>>>(partials, out, NB);
    } else {
        hipMemsetAsync(d_out, 0, sizeof(float), stream);
        bce_atomic_kernel<<<NB, BLK, 0, stream>>>(
            (const float4*)predict, (const float4*)target, out, n4);
    }
}